// Round 4
// baseline (979.996 us; speedup 1.0000x reference)
//
#include <hip/hip_runtime.h>
#include <hip/hip_bf16.h>

// ---------------------------------------------------------------------------
// StreamingQwenMoE round 4: 8-phase-template grouped GEMM (T3+T4+T5).
//   512 thr / 8 waves (2x4), BM=256, BK=64; 4 phases x 8 MFMA per K-tile.
//   A: global_load_lds, 3 buffers, issued 2 tiles ahead (pre-swizzled source).
//   B: f32 weights + fused block-scale dequant, reg-staged 2 tiles ahead
//      (named E/O sets), ds-written to swizzled LDS at P3 of the prior tile.
//   Counted s_waitcnt vmcnt(12) once per tile (never 0 mid-loop); 2 barriers
//   per phase; s_setprio(1) around each MFMA cluster; scales preloaded to LDS
//   so the vmcnt ledger is exact.
// Verified carried over: router/top8/dispatch, SwiGLU, C/D layout, XOR
// swizzle (r3: bank conflicts 4.2e7 -> 0), XCD-bijective block swizzle,
// atomic combine epilogues.
// ---------------------------------------------------------------------------

#define TT   2048
#define DD   2048
#define DFF  768
#define DSH  2048
#define EE   32
#define KTOP 8
#define CAP  1024

typedef _Float16 half8  __attribute__((ext_vector_type(8)));
typedef _Float16 half4v __attribute__((ext_vector_type(4)));
typedef float    f32x4  __attribute__((ext_vector_type(4)));

// ---------------- init: zero per-expert counters + slot->token map ----------
__global__ __launch_bounds__(256) void k_init(int* __restrict__ cnt,
                                              int* __restrict__ slot_tok) {
  int i = blockIdx.x * 256 + threadIdx.x;
  if (i < EE * CAP) slot_tok[i] = 0;   // unfilled slots -> token 0 (rows masked)
  if (i < EE) cnt[i] = 0;
}

__global__ __launch_bounds__(256) void k_zero(float* __restrict__ out) {
  int i = blockIdx.x * 256 + threadIdx.x;
  ((float4*)out)[i] = (float4){0.f, 0.f, 0.f, 0.f};
}

__global__ __launch_bounds__(256) void k_cast(const float* __restrict__ in,
                                              _Float16* __restrict__ out) {
  int i = blockIdx.x * 256 + threadIdx.x;
  float4 v = ((const float4*)in)[i];
  half4v h = { (_Float16)v.x, (_Float16)v.y, (_Float16)v.z, (_Float16)v.w };
  ((half4v*)out)[i] = h;
}

// ---------------- router: logits, top8, renorm, dispatch --------------------
__global__ __launch_bounds__(64) void k_router(
    const float* __restrict__ x, const float* __restrict__ rw,
    const float* __restrict__ wshg,
    float* __restrict__ shg, int* __restrict__ cnt,
    int* __restrict__ slot_tok, float* __restrict__ slot_w) {
  int t = blockIdx.x;
  int lane = threadIdx.x;
  const float* xr = x + (size_t)t * DD;
  float xv[32];
#pragma unroll
  for (int j = 0; j < 32; ++j) xv[j] = xr[lane + j * 64];

  __shared__ float lg[EE];
  for (int e = 0; e < EE; ++e) {
    const float* we = rw + (size_t)e * DD;
    float s = 0.f;
#pragma unroll
    for (int j = 0; j < 32; ++j) s += xv[j] * we[lane + j * 64];
#pragma unroll
    for (int off = 32; off > 0; off >>= 1) s += __shfl_down(s, off);
    if (lane == 0) lg[e] = s;
  }
  {
    float s = 0.f;
#pragma unroll
    for (int j = 0; j < 32; ++j) s += xv[j] * wshg[lane + j * 64];
#pragma unroll
    for (int off = 32; off > 0; off >>= 1) s += __shfl_down(s, off);
    if (lane == 0) shg[t] = 1.f / (1.f + expf(-s));
  }
  if (lane == 0) {
    unsigned used = 0;
    int sel[KTOP];
    float val[KTOP];
    for (int k = 0; k < KTOP; ++k) {
      float bv = -1e30f; int bi = 0;
      for (int e = 0; e < EE; ++e)
        if (!((used >> e) & 1) && lg[e] > bv) { bv = lg[e]; bi = e; }
      used |= (1u << bi);
      sel[k] = bi; val[k] = bv;
    }
    float mx = val[0], sum = 0.f;
    for (int k = 0; k < KTOP; ++k) { val[k] = expf(val[k] - mx); sum += val[k]; }
    float inv = 1.f / sum;
    for (int k = 0; k < KTOP; ++k) {
      int e = sel[k];
      int pos = atomicAdd(&cnt[e], 1);
      if (pos < CAP) {
        slot_tok[e * CAP + pos] = t;
        slot_w[e * CAP + pos] = val[k] * inv;
      }
    }
  }
}

// ---------------- 8-phase grouped GEMM ---------------------------------------
// C = A (rows x K, f16) * B (N x K, f32 + block scales)^T
// DUAL: gate+up, per-op BN=64, SwiGLU epilogue. single: BN=128.
// EPI: 0 = f16 OutH; 1 = atomic scatter w*val -> OutF; 2 = OutF += shg*val.
template<bool DUAL, bool GATHER, bool DEQ, int EPI, int NPB, int MBB, int KDIM>
__global__ __launch_bounds__(512, 2) void k_gemm(
    const _Float16* __restrict__ A,
    const float* __restrict__ B0f, const float* __restrict__ B1f,
    const float* __restrict__ S0, const float* __restrict__ S1,
    int sStrideE,
    _Float16* __restrict__ OutH, float* __restrict__ OutF,
    const float* __restrict__ shg,
    int ldA, int ldOut,
    long long strideAE, long long strideBE, long long strideOE,
    const int* __restrict__ cnt, int rowsConst,
    const int* __restrict__ slot_tok, const float* __restrict__ slot_w) {
  constexpr int BK = 64;
  constexpr int KT = KDIM / BK;        // 32 / 12 (even, >=4)
  constexpr int KS = KDIM / 128;       // scale blocks along K
  constexpr int NFE = DUAL ? 1 : 2;    // epilogue col-frags per op

  // bijective XCD swizzle: all m-blocks of pair (n,e) adjacent on one XCD
  const int f = blockIdx.x;
  const int xcd = f & 7;
  const int t0 = f >> 3;
  const int mb = t0 % MBB;
  const int pp = t0 / MBB;
  const int p  = pp * 8 + xcd;         // (NPB*E) % 8 == 0 for all uses
  const int nb = p % NPB;
  const int e  = p / NPB;

  int rows = cnt ? (cnt[e] > CAP ? CAP : cnt[e]) : rowsConst;
  const int rowBase = mb * 256;
  if (rowBase >= rows) return;
  const int nBase = nb * (DUAL ? 64 : 128);

  const int tid = threadIdx.x;
  const int lane = tid & 63;
  const int wave = tid >> 6;
  const int wr = wave >> 2;            // 0..1 : 128 rows each
  const int wc = wave & 3;             // 0..3

  __shared__ __align__(16) _Float16 sA[3][16384];   // 96 KB: 3 x (256x64)
  __shared__ __align__(16) _Float16 sB[2][8192];    // 32 KB: 2 x (128x64)
  __shared__ float sSc[2][16];

  const _Float16* Ae = A + (GATHER ? 0 : (long long)e * strideAE);
  const float* B0e = B0f + (long long)e * strideBE;
  const float* B1e = DUAL ? (B1f + (long long)e * strideBE) : nullptr;

  // scales -> LDS (keeps the vmcnt ledger exact in the main loop)
  if constexpr (DEQ) {
    const int sRow = (nBase >> 7) * KS;
    if (tid < KS) sSc[0][tid] = S0[(long long)e * sStrideE + sRow + tid];
    if (DUAL && tid >= 64 && tid < 64 + KS)
      sSc[1][tid - 64] = S1[(long long)e * sStrideE + sRow + tid - 64];
    __syncthreads();
  }

  // A staging addresses: source col pre-swizzled (LDS dest linear; rule #21)
  int aByte[4];
#pragma unroll
  for (int i = 0; i < 4; ++i) {
    int c = tid + i * 512;                        // 16B chunk id [0,2048)
    int row = c >> 3;                             // 0..255
    int colB = ((c & 7) << 4) ^ ((row & 7) << 4);
    int src = GATHER ? slot_tok[e * CAP + rowBase + row] : (rowBase + row);
    aByte[i] = src * (2 * ldA) + colB;            // < 2^31 for all uses
  }
  // B staging: 4 float4/thread; DUAL: i<2 -> gate rows, i>=2 -> up rows
  int bOff[4], wByte[4];
#pragma unroll
  for (int i = 0; i < 4; ++i) {
    int c = tid + i * 512;
    int rn = DUAL ? ((c & 1023) >> 4) : (c >> 4); // 0..63 | 0..127
    int c4 = (c & 15) * 4;                        // f32 col
    bOff[i] = (nBase + rn) * KDIM + c4;
    wByte[i] = ((DUAL && i >= 2) ? 8192 : 0) +
               ((((rn << 7) + (c4 << 1)) ^ ((rn & 7) << 4)));
  }

  f32x4 accG[8][NFE];
  f32x4 accU[DUAL ? 8 : 1][1];
#pragma unroll
  for (int m = 0; m < 8; ++m) {
#pragma unroll
    for (int n = 0; n < NFE; ++n) accG[m][n] = (f32x4){0.f, 0.f, 0.f, 0.f};
    if constexpr (DUAL) accU[m][0] = (f32x4){0.f, 0.f, 0.f, 0.f};
  }

  auto stageA = [&](int kt, int buf) {            // 4 DMA, wave-uniform base
#pragma unroll
    for (int i = 0; i < 4; ++i) {
      __builtin_amdgcn_global_load_lds(
          (const __attribute__((address_space(1))) void*)
              ((const char*)Ae + (long long)aByte[i] + kt * 128),
          (__attribute__((address_space(3))) void*)&sA[buf][(tid + i * 512) * 8],
          16, 0, 0);
    }
  };
  auto loadB = [&](int kt, float4 (&r)[4]) {      // 8 global loads / wave-pair
    const int ko = kt * BK;
#pragma unroll
    for (int i = 0; i < 4; ++i) {
      const float* src = (DUAL && i >= 2) ? B1e : B0e;
      r[i] = *(const float4*)(src + bOff[i] + ko);
    }
  };
  auto writeB = [&](int tw, float4 (&r)[4]) {     // dequant + swizzled ds_write
    float s0 = 1.f, s1 = 1.f;
    if constexpr (DEQ) {
      s0 = sSc[0][tw >> 1];
      if constexpr (DUAL) s1 = sSc[1][tw >> 1];
    }
    char* base = (char*)&sB[0][0] + (tw & 1) * 16384;
#pragma unroll
    for (int i = 0; i < 4; ++i) {
      float sc = (DUAL && i >= 2) ? s1 : s0;
      half4v h = { (_Float16)(r[i].x * sc), (_Float16)(r[i].y * sc),
                   (_Float16)(r[i].z * sc), (_Float16)(r[i].w * sc) };
      *(half4v*)(base + wByte[i]) = h;
    }
  };

  float4 rE[4], rO[4];

  // prologue: tiles 0,1 fully in flight; write sB[0]; one clean barrier
  loadB(0, rE); stageA(0, 0);
  loadB(1, rO); stageA(1, 1);
  asm volatile("s_waitcnt vmcnt(12)" ::: "memory");  // drain B(0) gl + A(0) dma
  writeB(0, rE);
  asm volatile("s_waitcnt lgkmcnt(0)" ::: "memory");
  __builtin_amdgcn_sched_barrier(0);
  __builtin_amdgcn_s_barrier();

  const int koffB0 = (lane >> 4) * 16;              // kk=0 frag col (bytes)

  auto tile = [&](int t, int bufR, int bufD, float4 (&rIss)[4], float4 (&rWr)[4]) {
    const char* pA = (const char*)&sA[0][0] + bufR * 32768;
    const char* pB = (const char*)&sB[0][0] + (t & 1) * 16384;
    half8 bg[2], bu[2], bs0[2], bs1[2];
#pragma unroll
    for (int ph = 0; ph < 4; ++ph) {
      // ---- issue + ds_reads (overlap other waves' MFMA of phase ph-1) ----
      if (ph == 0) {
        if (t + 2 < KT) loadB(t + 2, rIss);
        if constexpr (DUAL) {
          int rn = wc * 16 + (lane & 15);
          int rb = rn << 7, sw = (rn & 7) << 4;
          bg[0] = *(const half8*)(pB + ((rb + koffB0) ^ sw));
          bg[1] = *(const half8*)(pB + ((rb + koffB0 + 64) ^ sw));
          bu[0] = *(const half8*)(pB + 8192 + ((rb + koffB0) ^ sw));
          bu[1] = *(const half8*)(pB + 8192 + ((rb + koffB0 + 64) ^ sw));
        } else {
          int rn0 = wc * 32 + (lane & 15);
          int rb0 = rn0 << 7, sw0 = (rn0 & 7) << 4;
          bs0[0] = *(const half8*)(pB + ((rb0 + koffB0) ^ sw0));
          bs0[1] = *(const half8*)(pB + ((rb0 + koffB0 + 64) ^ sw0));
          int rn1 = rn0 + 16;
          int rb1 = rn1 << 7, sw1 = (rn1 & 7) << 4;
          bs1[0] = *(const half8*)(pB + ((rb1 + koffB0) ^ sw1));
          bs1[1] = *(const half8*)(pB + ((rb1 + koffB0 + 64) ^ sw1));
        }
      }
      if (ph == 1 && t + 2 < KT) stageA(t + 2, bufD);
      half8 a[2][2];
#pragma unroll
      for (int mm = 0; mm < 2; ++mm) {
        int r = wr * 128 + (2 * ph + mm) * 16 + (lane & 15);
        int rb = r << 7, sw = (r & 7) << 4;
        a[mm][0] = *(const half8*)(pA + ((rb + koffB0) ^ sw));
        a[mm][1] = *(const half8*)(pA + ((rb + koffB0 + 64) ^ sw));
      }
      if (ph == 3) {
        // counted drain: keep this tile's 12 ops in flight (T4)
        if (t + 2 < KT) { asm volatile("s_waitcnt vmcnt(12)" ::: "memory"); }
        else            { asm volatile("s_waitcnt vmcnt(0)"  ::: "memory"); }
        if (t + 1 < KT) writeB(t + 1, rWr);
      }
      __builtin_amdgcn_s_barrier();
      asm volatile("s_waitcnt lgkmcnt(0)" ::: "memory");
      __builtin_amdgcn_sched_barrier(0);
      __builtin_amdgcn_s_setprio(1);
#pragma unroll
      for (int mm = 0; mm < 2; ++mm) {
#pragma unroll
        for (int kk = 0; kk < 2; ++kk) {
          if constexpr (DUAL) {
            accG[2 * ph + mm][0] = __builtin_amdgcn_mfma_f32_16x16x32_f16(
                a[mm][kk], bg[kk], accG[2 * ph + mm][0], 0, 0, 0);
            accU[2 * ph + mm][0] = __builtin_amdgcn_mfma_f32_16x16x32_f16(
                a[mm][kk], bu[kk], accU[2 * ph + mm][0], 0, 0, 0);
          } else {
            accG[2 * ph + mm][0] = __builtin_amdgcn_mfma_f32_16x16x32_f16(
                a[mm][kk], bs0[kk], accG[2 * ph + mm][0], 0, 0, 0);
            accG[2 * ph + mm][1] = __builtin_amdgcn_mfma_f32_16x16x32_f16(
                a[mm][kk], bs1[kk], accG[2 * ph + mm][1], 0, 0, 0);
          }
        }
      }
      __builtin_amdgcn_s_setprio(0);
      __builtin_amdgcn_sched_barrier(0);
      __builtin_amdgcn_s_barrier();
    }
  };

  int bufR = 0, bufD = 2;
  for (int t2 = 0; t2 < KT; t2 += 2) {
    tile(t2, bufR, bufD, rE, rO);
    bufR = (bufR == 2) ? 0 : bufR + 1;
    bufD = (bufD == 2) ? 0 : bufD + 1;
    tile(t2 + 1, bufR, bufD, rO, rE);
    bufR = (bufR == 2) ? 0 : bufR + 1;
    bufD = (bufD == 2) ? 0 : bufD + 1;
  }

  // epilogue; C/D layout: col = lane&15, row = (lane>>4)*4 + i (verified)
#pragma unroll
  for (int m = 0; m < 8; ++m) {
#pragma unroll
    for (int i = 0; i < 4; ++i) {
      int row = rowBase + wr * 128 + m * 16 + (lane >> 4) * 4 + i;
      if (row < rows) {
        if constexpr (EPI == 1) {
          int tok = slot_tok[e * CAP + row];
          float w = slot_w[e * CAP + row];
#pragma unroll
          for (int n = 0; n < NFE; ++n) {
            int col = nBase + wc * 32 + n * 16 + (lane & 15);
            unsafeAtomicAdd(&OutF[(long long)tok * DD + col], w * accG[m][n][i]);
          }
        } else if constexpr (EPI == 2) {
          float g = shg[row];
#pragma unroll
          for (int n = 0; n < NFE; ++n) {
            int col = nBase + wc * 32 + n * 16 + (lane & 15);
            OutF[(long long)row * DD + col] += g * accG[m][n][i];
          }
        } else if constexpr (DUAL) {
          int col = nBase + wc * 16 + (lane & 15);
          float gv = accG[m][0][i];
          float uv = accU[m][0][i];
          OutH[(long long)e * strideOE + (long long)row * ldOut + col] =
              (_Float16)((gv / (1.f + __expf(-gv))) * uv);
        } else {
#pragma unroll
          for (int n = 0; n < 2; ++n) {
            int col = nBase + wc * 32 + n * 16 + (lane & 15);
            OutH[(long long)e * strideOE + (long long)row * ldOut + col] =
                (_Float16)accG[m][n][i];
          }
        }
      }
    }
  }
}

// ---------------------------------------------------------------------------
extern "C" void kernel_launch(void* const* d_in, const int* in_sizes, int n_in,
                              void* d_out, int out_size, void* d_ws, size_t ws_size,
                              hipStream_t stream) {
  (void)in_sizes; (void)n_in; (void)out_size; (void)ws_size;
  const float* x    = (const float*)d_in[0];
  const float* rw   = (const float*)d_in[1];
  const float* wg   = (const float*)d_in[2];
  const float* sg   = (const float*)d_in[3];
  const float* wu   = (const float*)d_in[4];
  const float* su   = (const float*)d_in[5];
  const float* wd   = (const float*)d_in[6];
  const float* sd   = (const float*)d_in[7];
  const float* wsg  = (const float*)d_in[8];
  const float* wsu  = (const float*)d_in[9];
  const float* wsd  = (const float*)d_in[10];
  const float* wshg = (const float*)d_in[11];
  float* out = (float*)d_out;

  // workspace (~67.4 MB)
  char* p = (char*)d_ws;
  auto alloc = [&](size_t bytes) {
    char* r = p;
    p += (bytes + 255) & ~(size_t)255;
    return r;
  };
  _Float16* x_h = (_Float16*)alloc((size_t)TT * DD * 2);
  _Float16* H   = (_Float16*)alloc((size_t)EE * CAP * DFF * 2);
  _Float16* Hsh = (_Float16*)alloc((size_t)TT * DSH * 2);
  float* shg    = (float*)alloc((size_t)TT * 4);
  int* cnt      = (int*)alloc((size_t)EE * 4);
  int* slot_tok = (int*)alloc((size_t)EE * CAP * 4);
  float* slot_w = (float*)alloc((size_t)EE * CAP * 4);

  k_init<<<(EE * CAP + 255) / 256, 256, 0, stream>>>(cnt, slot_tok);
  k_zero<<<(TT * DD / 4) / 256, 256, 0, stream>>>(out);
  k_cast<<<(TT * DD / 4) / 256, 256, 0, stream>>>(x, x_h);
  k_router<<<TT, 64, 0, stream>>>(x, rw, wshg, shg, cnt, slot_tok, slot_w);

  // routed gate+up: NP=12 (DFF/64), MB=4 (CAP/256), E=32 -> 1536 blocks
  k_gemm<true, true, true, 0, 12, 4, DD><<<1536, 512, 0, stream>>>(
      x_h, wg, wu, sg, su, (DFF / 128) * (DD / 128),
      H, nullptr, nullptr,
      DD, DFF,
      0LL, (long long)DFF * DD, (long long)CAP * DFF,
      cnt, 0, slot_tok, nullptr);

  // routed down + weighted atomic scatter: NP=16 (DD/128), MB=4 -> 2048 blocks
  k_gemm<false, false, true, 1, 16, 4, DFF><<<2048, 512, 0, stream>>>(
      H, wd, wd, sd, sd, (DD / 128) * (DFF / 128),
      nullptr, out, nullptr,
      DFF, DD,
      (long long)CAP * DFF, (long long)DD * DFF, 0LL,
      cnt, 0, slot_tok, slot_w);

  // shared gate+up: NP=32 (DSH/64), MB=8 (TT/256) -> 256 blocks
  k_gemm<true, false, false, 0, 32, 8, DD><<<256, 512, 0, stream>>>(
      x_h, wsg, wsu, nullptr, nullptr, 0,
      Hsh, nullptr, nullptr,
      DD, DSH,
      0LL, 0LL, 0LL,
      nullptr, TT, nullptr, nullptr);

  // shared down (out += shg*val, runs last): NP=16 (DD/128), MB=8 -> 128 blocks
  k_gemm<false, false, false, 2, 16, 8, DSH><<<128, 512, 0, stream>>>(
      Hsh, wsd, wsd, nullptr, nullptr, 0,
      nullptr, out, shg,
      DSH, DD,
      0LL, 0LL, 0LL,
      nullptr, TT, nullptr, nullptr);
}

// Round 5
// 956.268 us; speedup vs baseline: 1.0248x; 1.0248x over previous
//
#include <hip/hip_runtime.h>
#include <hip/hip_bf16.h>

// ---------------------------------------------------------------------------
// StreamingQwenMoE round 5: r3 structure (best: 708us) + surgical fixes:
//   (1) dequant scales preloaded to LDS -> no stray VMEM consumer in the main
//       loop; compiler no longer inserts per-tile vmcnt drains for scale loads.
//   (2) depth-3 B prefetch (3 named reg sets, vmcnt(20)) covering ~900cyc HBM.
//   (3) clamped (unconditional) staging issues -> exactly 12 VMEM ops/tile,
//       uniform ledger, exact compiler waitcnt analysis.
// r4's fine-grained 8-phase REGRESSED (8 MFMA per barrier-pair too small) and
// is abandoned; 1 barrier per K-tile retained.
// Verified carried: router/top8/dispatch, SwiGLU, C/D layout, XOR swizzle
// (bank conflicts 0), bijective XCD block swizzle, atomic combine epilogues.
// ---------------------------------------------------------------------------

#define TT   2048
#define DD   2048
#define DFF  768
#define DSH  2048
#define EE   32
#define KTOP 8
#define CAP  1024

typedef _Float16 half8  __attribute__((ext_vector_type(8)));
typedef _Float16 half4v __attribute__((ext_vector_type(4)));
typedef float    f32x4  __attribute__((ext_vector_type(4)));

// ---------------- init: zero per-expert counters + slot->token map ----------
__global__ __launch_bounds__(256) void k_init(int* __restrict__ cnt,
                                              int* __restrict__ slot_tok) {
  int i = blockIdx.x * 256 + threadIdx.x;
  if (i < EE * CAP) slot_tok[i] = 0;   // unfilled slots -> token 0 (rows masked)
  if (i < EE) cnt[i] = 0;
}

__global__ __launch_bounds__(256) void k_zero(float* __restrict__ out) {
  int i = blockIdx.x * 256 + threadIdx.x;
  ((float4*)out)[i] = (float4){0.f, 0.f, 0.f, 0.f};
}

__global__ __launch_bounds__(256) void k_cast(const float* __restrict__ in,
                                              _Float16* __restrict__ out) {
  int i = blockIdx.x * 256 + threadIdx.x;
  float4 v = ((const float4*)in)[i];
  half4v h = { (_Float16)v.x, (_Float16)v.y, (_Float16)v.z, (_Float16)v.w };
  ((half4v*)out)[i] = h;
}

// ---------------- router: logits, top8, renorm, dispatch --------------------
__global__ __launch_bounds__(64) void k_router(
    const float* __restrict__ x, const float* __restrict__ rw,
    const float* __restrict__ wshg,
    float* __restrict__ shg, int* __restrict__ cnt,
    int* __restrict__ slot_tok, float* __restrict__ slot_w) {
  int t = blockIdx.x;
  int lane = threadIdx.x;
  const float* xr = x + (size_t)t * DD;
  float xv[32];
#pragma unroll
  for (int j = 0; j < 32; ++j) xv[j] = xr[lane + j * 64];

  __shared__ float lg[EE];
  for (int e = 0; e < EE; ++e) {
    const float* we = rw + (size_t)e * DD;
    float s = 0.f;
#pragma unroll
    for (int j = 0; j < 32; ++j) s += xv[j] * we[lane + j * 64];
#pragma unroll
    for (int off = 32; off > 0; off >>= 1) s += __shfl_down(s, off);
    if (lane == 0) lg[e] = s;
  }
  {
    float s = 0.f;
#pragma unroll
    for (int j = 0; j < 32; ++j) s += xv[j] * wshg[lane + j * 64];
#pragma unroll
    for (int off = 32; off > 0; off >>= 1) s += __shfl_down(s, off);
    if (lane == 0) shg[t] = 1.f / (1.f + expf(-s));
  }
  if (lane == 0) {
    unsigned used = 0;
    int sel[KTOP];
    float val[KTOP];
    for (int k = 0; k < KTOP; ++k) {
      float bv = -1e30f; int bi = 0;
      for (int e = 0; e < EE; ++e)
        if (!((used >> e) & 1) && lg[e] > bv) { bv = lg[e]; bi = e; }
      used |= (1u << bi);
      sel[k] = bi; val[k] = bv;
    }
    float mx = val[0], sum = 0.f;
    for (int k = 0; k < KTOP; ++k) { val[k] = expf(val[k] - mx); sum += val[k]; }
    float inv = 1.f / sum;
    for (int k = 0; k < KTOP; ++k) {
      int e = sel[k];
      int pos = atomicAdd(&cnt[e], 1);
      if (pos < CAP) {
        slot_tok[e * CAP + pos] = t;
        slot_w[e * CAP + pos] = val[k] * inv;
      }
    }
  }
}

// ---------------- grouped GEMM: C = A (rows x K, f16) * B (N x K, f32)^T ----
// sA[3] via global_load_lds (pre-swizzled source), sB[2] reg-staged with fused
// dequant (scales from LDS); 1 s_barrier per K-tile; uniform vmcnt(20) ledger
// (per tile: 4 A-DMA + 8 B-loads; B issued 3 tiles ahead, A 2 ahead).
template<bool DUAL, bool GATHER, bool DEQ, int EPI, int NPB, int MBB, int KDIM>
__global__ __launch_bounds__(256, 2) void k_gemm(
    const _Float16* __restrict__ A,
    const float* __restrict__ B0f, const float* __restrict__ B1f,
    const float* __restrict__ S0, const float* __restrict__ S1,
    int sStrideE,
    _Float16* __restrict__ OutH, float* __restrict__ OutF,
    const float* __restrict__ shg,
    int ldA, int ldOut,
    long long strideAE, long long strideBE, long long strideOE,
    const int* __restrict__ cnt, int rowsConst,
    const int* __restrict__ slot_tok, const float* __restrict__ slot_w) {
  constexpr int BK = 64;
  constexpr int KT = KDIM / BK;              // 32 / 12 (>=3)
  constexpr int KS = KDIM / 128;             // scale blocks along K (<=16)
  constexpr int NF = DUAL ? 2 : 4;
  constexpr int BN = DUAL ? 64 : 128;
  constexpr int BCH = DUAL ? 4 : 8;          // float4 chunks / thread / operand

  // bijective XCD swizzle: all m-blocks of pair (n,e) adjacent on one XCD
  const int f = blockIdx.x;
  const int xcd = f & 7;
  const int t0 = f >> 3;
  const int mb = t0 % MBB;
  const int pp = t0 / MBB;
  const int p  = pp * 8 + xcd;               // (NPB*E) % 8 == 0 for all uses
  const int nb = p % NPB;
  const int e  = p / NPB;

  int rows = cnt ? (cnt[e] > CAP ? CAP : cnt[e]) : rowsConst;
  const int rowBase = mb * 128;
  if (rowBase >= rows) return;
  const int nBase = nb * BN;

  const int tid = threadIdx.x;
  const int lane = tid & 63;
  const int wave = tid >> 6;
  const int wr = wave >> 1;
  const int wc = wave & 1;

  __shared__ __align__(16) _Float16 sA[3][8192];   // 48 KB (128 x 64 f16 each)
  __shared__ __align__(16) _Float16 sB[2][8192];   // 32 KB
  __shared__ float sSc[2][16];

  const _Float16* Ae = A + (GATHER ? 0 : (long long)e * strideAE);
  const float* B0e = B0f + (long long)e * strideBE;
  const float* B1e = DUAL ? (B1f + (long long)e * strideBE) : nullptr;

  // scales -> LDS once (keeps the main loop free of stray VMEM consumers)
  if constexpr (DEQ) {
    const int sRow = (nBase >> 7) * KS;
    if (tid < KS) sSc[0][tid] = S0[(long long)e * sStrideE + sRow + tid];
    if (DUAL && tid >= 64 && tid < 64 + KS)
      sSc[1][tid - 64] = S1[(long long)e * sStrideE + sRow + tid - 64];
    __syncthreads();   // also drains all prior vmcnt -> clean ledger
  }

  // A staging (global_load_lds): LDS dest linear, source col pre-swizzled
  int aByte[4];
#pragma unroll
  for (int i = 0; i < 4; ++i) {
    int c = tid + i * 256;                   // 16B chunk id [0,1024)
    int row = c >> 3;                        // tile row 0..127
    int colB = ((c & 7) << 4) ^ ((row & 7) << 4);
    int src = GATHER ? slot_tok[e * CAP + rowBase + row] : (rowBase + row);
    aByte[i] = src * (2 * ldA) + colB;
  }
  // B staging: reg->cvt->swizzled LDS write
  int bOff[BCH], wByte[BCH];
#pragma unroll
  for (int i = 0; i < BCH; ++i) {
    int c = tid + i * 256;
    int rn = c >> 4;                         // [0, BN)
    int c4 = (c & 15) << 2;                  // f32 col 0..60 step 4
    bOff[i] = (nBase + rn) * KDIM + c4;
    wByte[i] = ((rn << 7) + (c4 << 1)) ^ ((rn & 7) << 4);
  }

  f32x4 accG[4][NF];
  f32x4 accU[DUAL ? 4 : 1][NF];
#pragma unroll
  for (int m = 0; m < 4; ++m)
#pragma unroll
    for (int n = 0; n < NF; ++n) {
      accG[m][n] = (f32x4){0.f, 0.f, 0.f, 0.f};
      if constexpr (DUAL) accU[m][n] = (f32x4){0.f, 0.f, 0.f, 0.f};
    }

  auto stageA = [&](int kt, int buf) {       // 4 DMA ops
#pragma unroll
    for (int i = 0; i < 4; ++i) {
      __builtin_amdgcn_global_load_lds(
          (const __attribute__((address_space(1))) void*)
              ((const char*)Ae + aByte[i] + kt * (BK * 2)),
          (__attribute__((address_space(3))) void*)&sA[buf][(tid + i * 256) * 8],
          16, 0, 0);
    }
  };
  auto loadB = [&](int kt, float4 (&r0)[BCH], float4 (&r1)[BCH]) {  // 8 loads
    const int ko = kt * BK;
#pragma unroll
    for (int i = 0; i < BCH; ++i) r0[i] = *(const float4*)(B0e + bOff[i] + ko);
    if constexpr (DUAL) {
#pragma unroll
      for (int i = 0; i < BCH; ++i) r1[i] = *(const float4*)(B1e + bOff[i] + ko);
    }
  };
  auto storeB = [&](int kt, float s0, float s1,
                    float4 (&r0)[BCH], float4 (&r1)[BCH]) {
    char* base = (char*)&sB[kt & 1][0];
#pragma unroll
    for (int i = 0; i < BCH; ++i) {
      half4v h = { (_Float16)(r0[i].x * s0), (_Float16)(r0[i].y * s0),
                   (_Float16)(r0[i].z * s0), (_Float16)(r0[i].w * s0) };
      *(half4v*)(base + wByte[i]) = h;
      if constexpr (DUAL) {
        half4v h1 = { (_Float16)(r1[i].x * s1), (_Float16)(r1[i].y * s1),
                      (_Float16)(r1[i].z * s1), (_Float16)(r1[i].w * s1) };
        *(half4v*)(base + 8192 + wByte[i]) = h1;
      }
    }
  };
  auto computeTile = [&](int ia, int ib) {
    const char* pA = (const char*)&sA[ia][0];
    const char* pB = (const char*)&sB[ib][0];
#pragma unroll
    for (int kk = 0; kk < 2; ++kk) {
      const int koff = kk * 32 + (lane >> 4) * 8;    // f16 elems
      half8 a[4];
#pragma unroll
      for (int m = 0; m < 4; ++m) {
        int r = wr * 64 + m * 16 + (lane & 15);
        int byt = ((r << 7) + (koff << 1)) ^ ((r & 7) << 4);
        a[m] = *(const half8*)(pA + byt);
      }
      if constexpr (DUAL) {
        half8 bg[2], bu[2];
#pragma unroll
        for (int n = 0; n < 2; ++n) {
          int rn = wc * 32 + n * 16 + (lane & 15);
          int byt = ((rn << 7) + (koff << 1)) ^ ((rn & 7) << 4);
          bg[n] = *(const half8*)(pB + byt);
          bu[n] = *(const half8*)(pB + 8192 + byt);
        }
#pragma unroll
        for (int m = 0; m < 4; ++m)
#pragma unroll
          for (int n = 0; n < 2; ++n) {
            accG[m][n] = __builtin_amdgcn_mfma_f32_16x16x32_f16(a[m], bg[n], accG[m][n], 0, 0, 0);
            accU[m][n] = __builtin_amdgcn_mfma_f32_16x16x32_f16(a[m], bu[n], accU[m][n], 0, 0, 0);
          }
      } else {
        half8 b[4];
#pragma unroll
        for (int n = 0; n < 4; ++n) {
          int rn = wc * 64 + n * 16 + (lane & 15);
          int byt = ((rn << 7) + (koff << 1)) ^ ((rn & 7) << 4);
          b[n] = *(const half8*)(pB + byt);
        }
#pragma unroll
        for (int m = 0; m < 4; ++m)
#pragma unroll
          for (int n = 0; n < 4; ++n)
            accG[m][n] = __builtin_amdgcn_mfma_f32_16x16x32_f16(a[m], b[n], accG[m][n], 0, 0, 0);
      }
    }
  };

  // 3 named B register sets (depth-3 prefetch; rule #20: no runtime indexing)
  float4 rA0[BCH], rA1[BCH], rB0[BCH], rB1[BCH], rC0[BCH], rC1[BCH];

  // prologue: exact issue order A0,B0,A1,B1,B2 (pinned) -> ledger = 24
  stageA(0, 0);
  __builtin_amdgcn_sched_barrier(0);
  loadB(0, rA0, rA1);
  __builtin_amdgcn_sched_barrier(0);
  stageA(1, 1);
  __builtin_amdgcn_sched_barrier(0);
  loadB(1, rB0, rB1);
  __builtin_amdgcn_sched_barrier(0);
  loadB(2, rC0, rC1);
  __builtin_amdgcn_sched_barrier(0);

  // one step: wait(20) | storeB(t) | lgkm(0) | barrier | issue A(t+2),B(t+3)
  //           | compute(t).  Clamped issues keep exactly 12 VMEM ops/tile.
  auto step = [&](int t, float4 (&r0)[BCH], float4 (&r1)[BCH],
                  int bufR, int bufW) {
    float s0 = 1.f, s1 = 1.f;
    if constexpr (DEQ) {
      s0 = sSc[0][t >> 1];                      // ds_read; latency hides under
      if constexpr (DUAL) s1 = sSc[1][t >> 1];  // the vmcnt wait below
    }
    asm volatile("s_waitcnt vmcnt(20)" ::: "memory");
    __builtin_amdgcn_sched_barrier(0);
    storeB(t, s0, s1, r0, r1);
    asm volatile("s_waitcnt lgkmcnt(0)" ::: "memory");
    __builtin_amdgcn_sched_barrier(0);
    __builtin_amdgcn_s_barrier();
    __builtin_amdgcn_sched_barrier(0);
    int ta = (t + 2 < KT) ? t + 2 : KT - 1;     // clamped re-stage: harmless,
    int tb = (t + 3 < KT) ? t + 3 : KT - 1;     // keeps ledger uniform
    stageA(ta, bufW);
    __builtin_amdgcn_sched_barrier(0);
    loadB(tb, r0, r1);
    __builtin_amdgcn_sched_barrier(0);
    computeTile(bufR, t & 1);
  };

  for (int kt = 0; kt < KT; kt += 3) {
    step(kt, rA0, rA1, 0, 2);
    if (kt + 1 < KT) step(kt + 1, rB0, rB1, 1, 0);
    if (kt + 2 < KT) step(kt + 2, rC0, rC1, 2, 1);
  }

  // epilogue; C/D layout: col = lane&15, row = (lane>>4)*4 + i (verified)
#pragma unroll
  for (int m = 0; m < 4; ++m) {
#pragma unroll
    for (int i = 0; i < 4; ++i) {
      int row = rowBase + wr * 64 + m * 16 + (lane >> 4) * 4 + i;
      if (row < rows) {
        if constexpr (EPI == 1) {
          int tok = slot_tok[e * CAP + row];
          float w = slot_w[e * CAP + row];
#pragma unroll
          for (int n = 0; n < NF; ++n) {
            int col = nBase + wc * 64 + n * 16 + (lane & 15);
            unsafeAtomicAdd(&OutF[(long long)tok * DD + col], w * accG[m][n][i]);
          }
        } else if constexpr (EPI == 2) {
          float g = shg[row];
#pragma unroll
          for (int n = 0; n < NF; ++n) {
            int col = nBase + wc * 64 + n * 16 + (lane & 15);
            long long o = (long long)row * DD + col;
            OutF[o] += g * accG[m][n][i];
          }
        } else {
          long long outBase = (long long)e * strideOE;
#pragma unroll
          for (int n = 0; n < NF; ++n) {
            int col = nBase + (DUAL ? wc * 32 : wc * 64) + n * 16 + (lane & 15);
            long long o = outBase + (long long)row * ldOut + col;
            if constexpr (DUAL) {
              float gv = accG[m][n][i];
              float uv = accU[m][n][i];
              OutH[o] = (_Float16)((gv / (1.f + __expf(-gv))) * uv);
            } else {
              OutH[o] = (_Float16)accG[m][n][i];
            }
          }
        }
      }
    }
  }
}

// ---------------------------------------------------------------------------
extern "C" void kernel_launch(void* const* d_in, const int* in_sizes, int n_in,
                              void* d_out, int out_size, void* d_ws, size_t ws_size,
                              hipStream_t stream) {
  (void)in_sizes; (void)n_in; (void)out_size; (void)ws_size;
  const float* x    = (const float*)d_in[0];
  const float* rw   = (const float*)d_in[1];
  const float* wg   = (const float*)d_in[2];
  const float* sg   = (const float*)d_in[3];
  const float* wu   = (const float*)d_in[4];
  const float* su   = (const float*)d_in[5];
  const float* wd   = (const float*)d_in[6];
  const float* sd   = (const float*)d_in[7];
  const float* wsg  = (const float*)d_in[8];
  const float* wsu  = (const float*)d_in[9];
  const float* wsd  = (const float*)d_in[10];
  const float* wshg = (const float*)d_in[11];
  float* out = (float*)d_out;

  // workspace (~67.4 MB)
  char* p = (char*)d_ws;
  auto alloc = [&](size_t bytes) {
    char* r = p;
    p += (bytes + 255) & ~(size_t)255;
    return r;
  };
  _Float16* x_h = (_Float16*)alloc((size_t)TT * DD * 2);
  _Float16* H   = (_Float16*)alloc((size_t)EE * CAP * DFF * 2);
  _Float16* Hsh = (_Float16*)alloc((size_t)TT * DSH * 2);
  float* shg    = (float*)alloc((size_t)TT * 4);
  int* cnt      = (int*)alloc((size_t)EE * 4);
  int* slot_tok = (int*)alloc((size_t)EE * CAP * 4);
  float* slot_w = (float*)alloc((size_t)EE * CAP * 4);

  k_init<<<(EE * CAP + 255) / 256, 256, 0, stream>>>(cnt, slot_tok);
  k_zero<<<(TT * DD / 4) / 256, 256, 0, stream>>>(out);
  k_cast<<<(TT * DD / 4) / 256, 256, 0, stream>>>(x, x_h);
  k_router<<<TT, 64, 0, stream>>>(x, rw, wshg, shg, cnt, slot_tok, slot_w);

  // routed gate+up: NP=12, MB=8, E=32 -> 3072 flat blocks
  k_gemm<true, true, true, 0, 12, 8, DD><<<3072, 256, 0, stream>>>(
      x_h, wg, wu, sg, su, (DFF / 128) * (DD / 128),
      H, nullptr, nullptr,
      DD, DFF,
      0LL, (long long)DFF * DD, (long long)CAP * DFF,
      cnt, 0, slot_tok, nullptr);

  // routed down + weighted atomic scatter: NP=16, MB=8, E=32 -> 4096 blocks
  k_gemm<false, false, true, 1, 16, 8, DFF><<<4096, 256, 0, stream>>>(
      H, wd, wd, sd, sd, (DD / 128) * (DFF / 128),
      nullptr, out, nullptr,
      DFF, DD,
      (long long)CAP * DFF, (long long)DD * DFF, 0LL,
      cnt, 0, slot_tok, slot_w);

  // shared gate+up: NP=32, MB=16, E=1 -> 512 blocks
  k_gemm<true, false, false, 0, 32, 16, DD><<<512, 256, 0, stream>>>(
      x_h, wsg, wsu, nullptr, nullptr, 0,
      Hsh, nullptr, nullptr,
      DD, DSH,
      0LL, 0LL, 0LL,
      nullptr, TT, nullptr, nullptr);

  // shared down (out += shg*val, runs last): NP=16, MB=16, E=1 -> 256 blocks
  k_gemm<false, false, false, 2, 16, 16, DSH><<<256, 256, 0, stream>>>(
      Hsh, wsd, wsd, nullptr, nullptr, 0,
      nullptr, out, shg,
      DSH, DD,
      0LL, 0LL, 0LL,
      nullptr, TT, nullptr, nullptr);
}

// Round 6
// 913.842 us; speedup vs baseline: 1.0724x; 1.0464x over previous
//
#include <hip/hip_runtime.h>
#include <hip/hip_bf16.h>

// ---------------------------------------------------------------------------
// StreamingQwenMoE round 6: r3 structure (best known: 708us, LDS=81920 exactly,
// 2 blocks/CU) + depth-3 B/scale prefetch with ZERO LDS growth.
//   r4/r5 lesson (measured twice): LDS > 81920 -> 1 block/CU -> regression.
//   - B + scale prefetched 3 tiles ahead (3 named reg sets), A 2 ahead (3 LDS
//     bufs via global_load_lds).
//   - scale = 1 inline-asm global_load_dword per operand per tile (guaranteed
//     VMEM; keeps the vmcnt ledger exact; r3 wastefully issued ~8).
//   - uniform ledger: every step issues 4 A-DMA + 8 B + (2|1|0) S ops (tail
//     clamped); counted wait = newer-than-A(t) = 24/22/20, never 0 mid-loop.
// Verified carried: router/top8/dispatch, SwiGLU, C/D layout, XOR swizzle
// (bank conflicts 0), bijective XCD block swizzle, atomic combine epilogues.
// ---------------------------------------------------------------------------

#define TT   2048
#define DD   2048
#define DFF  768
#define DSH  2048
#define EE   32
#define KTOP 8
#define CAP  1024

typedef _Float16 half8  __attribute__((ext_vector_type(8)));
typedef _Float16 half4v __attribute__((ext_vector_type(4)));
typedef float    f32x4  __attribute__((ext_vector_type(4)));

// ---------------- init: zero per-expert counters + slot->token map ----------
__global__ __launch_bounds__(256) void k_init(int* __restrict__ cnt,
                                              int* __restrict__ slot_tok) {
  int i = blockIdx.x * 256 + threadIdx.x;
  if (i < EE * CAP) slot_tok[i] = 0;   // unfilled slots -> token 0 (rows masked)
  if (i < EE) cnt[i] = 0;
}

__global__ __launch_bounds__(256) void k_zero(float* __restrict__ out) {
  int i = blockIdx.x * 256 + threadIdx.x;
  ((float4*)out)[i] = (float4){0.f, 0.f, 0.f, 0.f};
}

__global__ __launch_bounds__(256) void k_cast(const float* __restrict__ in,
                                              _Float16* __restrict__ out) {
  int i = blockIdx.x * 256 + threadIdx.x;
  float4 v = ((const float4*)in)[i];
  half4v h = { (_Float16)v.x, (_Float16)v.y, (_Float16)v.z, (_Float16)v.w };
  ((half4v*)out)[i] = h;
}

// ---------------- router: logits, top8, renorm, dispatch --------------------
__global__ __launch_bounds__(64) void k_router(
    const float* __restrict__ x, const float* __restrict__ rw,
    const float* __restrict__ wshg,
    float* __restrict__ shg, int* __restrict__ cnt,
    int* __restrict__ slot_tok, float* __restrict__ slot_w) {
  int t = blockIdx.x;
  int lane = threadIdx.x;
  const float* xr = x + (size_t)t * DD;
  float xv[32];
#pragma unroll
  for (int j = 0; j < 32; ++j) xv[j] = xr[lane + j * 64];

  __shared__ float lg[EE];
  for (int e = 0; e < EE; ++e) {
    const float* we = rw + (size_t)e * DD;
    float s = 0.f;
#pragma unroll
    for (int j = 0; j < 32; ++j) s += xv[j] * we[lane + j * 64];
#pragma unroll
    for (int off = 32; off > 0; off >>= 1) s += __shfl_down(s, off);
    if (lane == 0) lg[e] = s;
  }
  {
    float s = 0.f;
#pragma unroll
    for (int j = 0; j < 32; ++j) s += xv[j] * wshg[lane + j * 64];
#pragma unroll
    for (int off = 32; off > 0; off >>= 1) s += __shfl_down(s, off);
    if (lane == 0) shg[t] = 1.f / (1.f + expf(-s));
  }
  if (lane == 0) {
    unsigned used = 0;
    int sel[KTOP];
    float val[KTOP];
    for (int k = 0; k < KTOP; ++k) {
      float bv = -1e30f; int bi = 0;
      for (int e = 0; e < EE; ++e)
        if (!((used >> e) & 1) && lg[e] > bv) { bv = lg[e]; bi = e; }
      used |= (1u << bi);
      sel[k] = bi; val[k] = bv;
    }
    float mx = val[0], sum = 0.f;
    for (int k = 0; k < KTOP; ++k) { val[k] = expf(val[k] - mx); sum += val[k]; }
    float inv = 1.f / sum;
    for (int k = 0; k < KTOP; ++k) {
      int e = sel[k];
      int pos = atomicAdd(&cnt[e], 1);
      if (pos < CAP) {
        slot_tok[e * CAP + pos] = t;
        slot_w[e * CAP + pos] = val[k] * inv;
      }
    }
  }
}

__device__ __forceinline__ float gload_f32(const float* p) {
  float r;
  asm volatile("global_load_dword %0, %1, off" : "=v"(r) : "v"(p) : "memory");
  return r;   // NOT ready until a vmcnt wait; consumers fenced by sched_barrier
}

// ---------------- grouped GEMM: C = A (rows x K, f16) * B (N x K, f32)^T ----
// sA[3] via global_load_lds (pre-swizzled source, depth-2), sB[2] reg-staged
// with fused dequant (B + scale prefetched depth-3, named reg sets);
// 1 s_barrier per K-tile; counted vmcnt (24/22/20), never 0 mid-loop.
template<bool DUAL, bool GATHER, bool DEQ, int EPI, int NPB, int MBB, int KDIM>
__global__ __launch_bounds__(256, 2) void k_gemm(
    const _Float16* __restrict__ A,
    const float* __restrict__ B0f, const float* __restrict__ B1f,
    const float* __restrict__ S0, const float* __restrict__ S1,
    int sStrideE,
    _Float16* __restrict__ OutH, float* __restrict__ OutF,
    const float* __restrict__ shg,
    int ldA, int ldOut,
    long long strideAE, long long strideBE, long long strideOE,
    const int* __restrict__ cnt, int rowsConst,
    const int* __restrict__ slot_tok, const float* __restrict__ slot_w) {
  constexpr int BK = 64;
  constexpr int KT = KDIM / BK;              // 32 / 12 (>=4)
  constexpr int KS = KDIM / 128;             // scale blocks along K
  constexpr int NF = DUAL ? 2 : 4;
  constexpr int BN = DUAL ? 64 : 128;
  constexpr int BCH = DUAL ? 4 : 8;          // float4 chunks / thread / operand

  // bijective XCD swizzle: all m-blocks of pair (n,e) adjacent on one XCD
  const int f = blockIdx.x;
  const int xcd = f & 7;
  const int t0 = f >> 3;
  const int mb = t0 % MBB;
  const int pp = t0 / MBB;
  const int p  = pp * 8 + xcd;               // (NPB*E) % 8 == 0 for all uses
  const int nb = p % NPB;
  const int e  = p / NPB;

  int rows = cnt ? (cnt[e] > CAP ? CAP : cnt[e]) : rowsConst;
  const int rowBase = mb * 128;
  if (rowBase >= rows) return;
  const int nBase = nb * BN;

  const int tid = threadIdx.x;
  const int lane = tid & 63;
  const int wave = tid >> 6;
  const int wr = wave >> 1;
  const int wc = wave & 1;

  __shared__ __align__(16) _Float16 sA[3][8192];   // 48 KB
  __shared__ __align__(16) _Float16 sB[2][8192];   // 32 KB  (total 81920 B)

  const _Float16* Ae = A + (GATHER ? 0 : (long long)e * strideAE);
  const float* B0e = B0f + (long long)e * strideBE;
  const float* B1e = DUAL ? (B1f + (long long)e * strideBE) : nullptr;
  const float* S0e = DEQ ? (S0 + (long long)e * sStrideE + (nBase >> 7) * KS)
                         : nullptr;
  const float* S1e = (DEQ && DUAL)
                         ? (S1 + (long long)e * sStrideE + (nBase >> 7) * KS)
                         : nullptr;

  // A staging (global_load_lds): LDS dest linear, source col pre-swizzled
  int aByte[4];
#pragma unroll
  for (int i = 0; i < 4; ++i) {
    int c = tid + i * 256;                   // 16B chunk id [0,1024)
    int row = c >> 3;                        // tile row 0..127
    int colB = ((c & 7) << 4) ^ ((row & 7) << 4);
    int src = GATHER ? slot_tok[e * CAP + rowBase + row] : (rowBase + row);
    aByte[i] = src * (2 * ldA) + colB;
  }
  // B staging: reg->cvt->swizzled LDS write
  int bOff[BCH], wByte[BCH];
#pragma unroll
  for (int i = 0; i < BCH; ++i) {
    int c = tid + i * 256;
    int rn = c >> 4;                         // [0, BN)
    int c4 = (c & 15) << 2;                  // f32 col 0..60 step 4
    bOff[i] = (nBase + rn) * KDIM + c4;
    wByte[i] = ((rn << 7) + (c4 << 1)) ^ ((rn & 7) << 4);
  }

  f32x4 accG[4][NF];
  f32x4 accU[DUAL ? 4 : 1][NF];
#pragma unroll
  for (int m = 0; m < 4; ++m)
#pragma unroll
    for (int n = 0; n < NF; ++n) {
      accG[m][n] = (f32x4){0.f, 0.f, 0.f, 0.f};
      if constexpr (DUAL) accU[m][n] = (f32x4){0.f, 0.f, 0.f, 0.f};
    }

  auto stageA = [&](int kt, int buf) {       // 4 DMA ops (vmcnt)
#pragma unroll
    for (int i = 0; i < 4; ++i) {
      __builtin_amdgcn_global_load_lds(
          (const __attribute__((address_space(1))) void*)
              ((const char*)Ae + aByte[i] + kt * (BK * 2)),
          (__attribute__((address_space(3))) void*)&sA[buf][(tid + i * 256) * 8],
          16, 0, 0);
    }
  };
  // B tile + its scales: 8 vector loads + (2|1|0) asm scale loads
  auto loadBS = [&](int kt, float4 (&r0)[BCH], float4 (&r1)[BCH],
                    float& s0, float& s1) {
    const int ko = kt * BK;
#pragma unroll
    for (int i = 0; i < BCH; ++i) r0[i] = *(const float4*)(B0e + bOff[i] + ko);
    if constexpr (DUAL) {
#pragma unroll
      for (int i = 0; i < BCH; ++i) r1[i] = *(const float4*)(B1e + bOff[i] + ko);
    }
    if constexpr (DEQ) {
      s0 = gload_f32(S0e + (kt >> 1));
      if constexpr (DUAL) s1 = gload_f32(S1e + (kt >> 1));
    }
  };
  auto storeB = [&](int kt, float s0, float s1,
                    float4 (&r0)[BCH], float4 (&r1)[BCH]) {
    if constexpr (!DEQ) { s0 = 1.f; s1 = 1.f; }
    char* base = (char*)&sB[kt & 1][0];
#pragma unroll
    for (int i = 0; i < BCH; ++i) {
      half4v h = { (_Float16)(r0[i].x * s0), (_Float16)(r0[i].y * s0),
                   (_Float16)(r0[i].z * s0), (_Float16)(r0[i].w * s0) };
      *(half4v*)(base + wByte[i]) = h;
      if constexpr (DUAL) {
        half4v h1 = { (_Float16)(r1[i].x * s1), (_Float16)(r1[i].y * s1),
                      (_Float16)(r1[i].z * s1), (_Float16)(r1[i].w * s1) };
        *(half4v*)(base + 8192 + wByte[i]) = h1;
      }
    }
  };
  auto computeTile = [&](int ia, int ib) {
    const char* pA = (const char*)&sA[ia][0];
    const char* pB = (const char*)&sB[ib][0];
#pragma unroll
    for (int kk = 0; kk < 2; ++kk) {
      const int koff = kk * 32 + (lane >> 4) * 8;    // f16 elems
      half8 a[4];
#pragma unroll
      for (int m = 0; m < 4; ++m) {
        int r = wr * 64 + m * 16 + (lane & 15);
        int byt = ((r << 7) + (koff << 1)) ^ ((r & 7) << 4);
        a[m] = *(const half8*)(pA + byt);
      }
      if constexpr (DUAL) {
        half8 bg[2], bu[2];
#pragma unroll
        for (int n = 0; n < 2; ++n) {
          int rn = wc * 32 + n * 16 + (lane & 15);
          int byt = ((rn << 7) + (koff << 1)) ^ ((rn & 7) << 4);
          bg[n] = *(const half8*)(pB + byt);
          bu[n] = *(const half8*)(pB + 8192 + byt);
        }
#pragma unroll
        for (int m = 0; m < 4; ++m)
#pragma unroll
          for (int n = 0; n < 2; ++n) {
            accG[m][n] = __builtin_amdgcn_mfma_f32_16x16x32_f16(a[m], bg[n], accG[m][n], 0, 0, 0);
            accU[m][n] = __builtin_amdgcn_mfma_f32_16x16x32_f16(a[m], bu[n], accU[m][n], 0, 0, 0);
          }
      } else {
        half8 b[4];
#pragma unroll
        for (int n = 0; n < 4; ++n) {
          int rn = wc * 64 + n * 16 + (lane & 15);
          int byt = ((rn << 7) + (koff << 1)) ^ ((rn & 7) << 4);
          b[n] = *(const half8*)(pB + byt);
        }
#pragma unroll
        for (int m = 0; m < 4; ++m)
#pragma unroll
          for (int n = 0; n < 4; ++n)
            accG[m][n] = __builtin_amdgcn_mfma_f32_16x16x32_f16(a[m], b[n], accG[m][n], 0, 0, 0);
      }
    }
  };

  // 3 named B register sets + scale regs (depth-3; rule #20: no runtime index)
  float4 rA0[BCH], rA1[BCH], rB0[BCH], rB1[BCH], rC0[BCH], rC1[BCH];
  float sA0 = 1.f, sA1 = 1.f, sB0s = 1.f, sB1s = 1.f, sC0 = 1.f, sC1 = 1.f;

  // prologue, pinned order: B0,S0 | A0 | B1,S1 | A1 | B2,S2
  loadBS(0, rA0, rA1, sA0, sA1);
  __builtin_amdgcn_sched_barrier(0);
  stageA(0, 0);
  __builtin_amdgcn_sched_barrier(0);
  loadBS(1, rB0, rB1, sB0s, sB1s);
  __builtin_amdgcn_sched_barrier(0);
  stageA(1, 1);
  __builtin_amdgcn_sched_barrier(0);
  loadBS(2, rC0, rC1, sC0, sC1);
  __builtin_amdgcn_sched_barrier(0);

  // step t: wait(W) | storeB(t) | lgkm0 | barrier | issue A(t+2), BS(t+3)
  //         | compute(t).  Clamped tail issues keep the ledger uniform.
  // W = ops newer than A(t) at the wait = A + 2*(B+S) = 24 / 22 / 20.
  auto step = [&](int t, float4 (&r0)[BCH], float4 (&r1)[BCH],
                  float& s0, float& s1, int bufR, int bufW) {
    if constexpr (DUAL)      asm volatile("s_waitcnt vmcnt(24)" ::: "memory");
    else if constexpr (DEQ)  asm volatile("s_waitcnt vmcnt(22)" ::: "memory");
    else                     asm volatile("s_waitcnt vmcnt(20)" ::: "memory");
    __builtin_amdgcn_sched_barrier(0);
    storeB(t, s0, s1, r0, r1);
    asm volatile("s_waitcnt lgkmcnt(0)" ::: "memory");
    __builtin_amdgcn_sched_barrier(0);
    __builtin_amdgcn_s_barrier();
    __builtin_amdgcn_sched_barrier(0);
    int ta = (t + 2 < KT) ? t + 2 : KT - 1;   // clamped: harmless, uniform
    int tb = (t + 3 < KT) ? t + 3 : KT - 1;
    stageA(ta, bufW);
    __builtin_amdgcn_sched_barrier(0);
    loadBS(tb, r0, r1, s0, s1);
    __builtin_amdgcn_sched_barrier(0);
    computeTile(bufR, t & 1);
  };

  for (int kt = 0; kt < KT; kt += 3) {
    step(kt, rA0, rA1, sA0, sA1, kt % 3, (kt + 2) % 3);
    if (kt + 1 < KT) step(kt + 1, rB0, rB1, sB0s, sB1s, (kt + 1) % 3, kt % 3);
    if (kt + 2 < KT) step(kt + 2, rC0, rC1, sC0, sC1, (kt + 2) % 3, (kt + 1) % 3);
  }

  // epilogue; C/D layout: col = lane&15, row = (lane>>4)*4 + i (verified)
#pragma unroll
  for (int m = 0; m < 4; ++m) {
#pragma unroll
    for (int i = 0; i < 4; ++i) {
      int row = rowBase + wr * 64 + m * 16 + (lane >> 4) * 4 + i;
      if (row < rows) {
        if constexpr (EPI == 1) {
          int tok = slot_tok[e * CAP + row];
          float w = slot_w[e * CAP + row];
#pragma unroll
          for (int n = 0; n < NF; ++n) {
            int col = nBase + wc * 64 + n * 16 + (lane & 15);
            unsafeAtomicAdd(&OutF[(long long)tok * DD + col], w * accG[m][n][i]);
          }
        } else if constexpr (EPI == 2) {
          float g = shg[row];
#pragma unroll
          for (int n = 0; n < NF; ++n) {
            int col = nBase + wc * 64 + n * 16 + (lane & 15);
            long long o = (long long)row * DD + col;
            OutF[o] += g * accG[m][n][i];
          }
        } else {
          long long outBase = (long long)e * strideOE;
#pragma unroll
          for (int n = 0; n < NF; ++n) {
            int col = nBase + (DUAL ? wc * 32 : wc * 64) + n * 16 + (lane & 15);
            long long o = outBase + (long long)row * ldOut + col;
            if constexpr (DUAL) {
              float gv = accG[m][n][i];
              float uv = accU[m][n][i];
              OutH[o] = (_Float16)((gv / (1.f + __expf(-gv))) * uv);
            } else {
              OutH[o] = (_Float16)accG[m][n][i];
            }
          }
        }
      }
    }
  }
}

// ---------------------------------------------------------------------------
extern "C" void kernel_launch(void* const* d_in, const int* in_sizes, int n_in,
                              void* d_out, int out_size, void* d_ws, size_t ws_size,
                              hipStream_t stream) {
  (void)in_sizes; (void)n_in; (void)out_size; (void)ws_size;
  const float* x    = (const float*)d_in[0];
  const float* rw   = (const float*)d_in[1];
  const float* wg   = (const float*)d_in[2];
  const float* sg   = (const float*)d_in[3];
  const float* wu   = (const float*)d_in[4];
  const float* su   = (const float*)d_in[5];
  const float* wd   = (const float*)d_in[6];
  const float* sd   = (const float*)d_in[7];
  const float* wsg  = (const float*)d_in[8];
  const float* wsu  = (const float*)d_in[9];
  const float* wsd  = (const float*)d_in[10];
  const float* wshg = (const float*)d_in[11];
  float* out = (float*)d_out;

  // workspace (~67.4 MB)
  char* p = (char*)d_ws;
  auto alloc = [&](size_t bytes) {
    char* r = p;
    p += (bytes + 255) & ~(size_t)255;
    return r;
  };
  _Float16* x_h = (_Float16*)alloc((size_t)TT * DD * 2);
  _Float16* H   = (_Float16*)alloc((size_t)EE * CAP * DFF * 2);
  _Float16* Hsh = (_Float16*)alloc((size_t)TT * DSH * 2);
  float* shg    = (float*)alloc((size_t)TT * 4);
  int* cnt      = (int*)alloc((size_t)EE * 4);
  int* slot_tok = (int*)alloc((size_t)EE * CAP * 4);
  float* slot_w = (float*)alloc((size_t)EE * CAP * 4);

  k_init<<<(EE * CAP + 255) / 256, 256, 0, stream>>>(cnt, slot_tok);
  k_zero<<<(TT * DD / 4) / 256, 256, 0, stream>>>(out);
  k_cast<<<(TT * DD / 4) / 256, 256, 0, stream>>>(x, x_h);
  k_router<<<TT, 64, 0, stream>>>(x, rw, wshg, shg, cnt, slot_tok, slot_w);

  // routed gate+up: NP=12, MB=8, E=32 -> 3072 flat blocks
  k_gemm<true, true, true, 0, 12, 8, DD><<<3072, 256, 0, stream>>>(
      x_h, wg, wu, sg, su, (DFF / 128) * (DD / 128),
      H, nullptr, nullptr,
      DD, DFF,
      0LL, (long long)DFF * DD, (long long)CAP * DFF,
      cnt, 0, slot_tok, nullptr);

  // routed down + weighted atomic scatter: NP=16, MB=8, E=32 -> 4096 blocks
  k_gemm<false, false, true, 1, 16, 8, DFF><<<4096, 256, 0, stream>>>(
      H, wd, wd, sd, sd, (DD / 128) * (DFF / 128),
      nullptr, out, nullptr,
      DFF, DD,
      (long long)CAP * DFF, (long long)DD * DFF, 0LL,
      cnt, 0, slot_tok, slot_w);

  // shared gate+up: NP=32, MB=16, E=1 -> 512 blocks
  k_gemm<true, false, false, 0, 32, 16, DD><<<512, 256, 0, stream>>>(
      x_h, wsg, wsu, nullptr, nullptr, 0,
      Hsh, nullptr, nullptr,
      DD, DSH,
      0LL, 0LL, 0LL,
      nullptr, TT, nullptr, nullptr);

  // shared down (out += shg*val, runs last): NP=16, MB=16, E=1 -> 256 blocks
  k_gemm<false, false, false, 2, 16, 16, DSH><<<256, 256, 0, stream>>>(
      Hsh, wsd, wsd, nullptr, nullptr, 0,
      nullptr, out, shg,
      DSH, DD,
      0LL, 0LL, 0LL,
      nullptr, TT, nullptr, nullptr);
}

// Round 7
// 681.118 us; speedup vs baseline: 1.4388x; 1.3417x over previous
//
#include <hip/hip_runtime.h>
#include <hip/hip_bf16.h>

// ---------------------------------------------------------------------------
// StreamingQwenMoE round 7: r3 GEMM loop VERBATIM (best verified: 708us) +
// atomic-free combine:
//   - down-GEMM epilogue: 33.5M global f32 atomics REPLACED by plain f16
//     stores into token-major pair buffer Yp[T*K, D] (w folded in).
//   - new k_combine: out[t] = sum_k Yp[t*8+k] (per-token block, no atomics,
//     overwrites all of out -> k_zero dropped). shared-down (+=) runs after.
//   - router additionally emits slot_pair (slot -> t*8+k) and pair_pos
//     (capacity keep-mask, exact reference semantics).
// r4/r5/r6 pipeline experiments reverted (measured: 8-phase@1blk/CU -27%,
// LDS>80KB halves occupancy, depth-3 prefetch null on gate+up, clamped tail
// loads regressed the KT=12 down-GEMM).
// ws: 134.5 MB (was 67.4) -- if post-timing diverges, ws_size is the cause.
// ---------------------------------------------------------------------------

#define TT   2048
#define DD   2048
#define DFF  768
#define DSH  2048
#define EE   32
#define KTOP 8
#define CAP  1024

typedef _Float16 half8  __attribute__((ext_vector_type(8)));
typedef _Float16 half4v __attribute__((ext_vector_type(4)));
typedef float    f32x4  __attribute__((ext_vector_type(4)));

// ---------------- init: zero per-expert counters + slot->token map ----------
__global__ __launch_bounds__(256) void k_init(int* __restrict__ cnt,
                                              int* __restrict__ slot_tok) {
  int i = blockIdx.x * 256 + threadIdx.x;
  if (i < EE * CAP) slot_tok[i] = 0;   // unfilled slots -> token 0 (rows masked)
  if (i < EE) cnt[i] = 0;
}

// ---------------- f32 -> f16 cast ---------------------------------------
__global__ __launch_bounds__(256) void k_cast(const float* __restrict__ in,
                                              _Float16* __restrict__ out) {
  int i = blockIdx.x * 256 + threadIdx.x;
  float4 v = ((const float4*)in)[i];
  half4v h = { (_Float16)v.x, (_Float16)v.y, (_Float16)v.z, (_Float16)v.w };
  ((half4v*)out)[i] = h;
}

// ---------------- router: logits, top8, renorm, dispatch --------------------
__global__ __launch_bounds__(64) void k_router(
    const float* __restrict__ x, const float* __restrict__ rw,
    const float* __restrict__ wshg,
    float* __restrict__ shg, int* __restrict__ cnt,
    int* __restrict__ slot_tok, float* __restrict__ slot_w,
    int* __restrict__ slot_pair, int* __restrict__ pair_pos) {
  int t = blockIdx.x;
  int lane = threadIdx.x;
  const float* xr = x + (size_t)t * DD;
  float xv[32];
#pragma unroll
  for (int j = 0; j < 32; ++j) xv[j] = xr[lane + j * 64];

  __shared__ float lg[EE];
  for (int e = 0; e < EE; ++e) {
    const float* we = rw + (size_t)e * DD;
    float s = 0.f;
#pragma unroll
    for (int j = 0; j < 32; ++j) s += xv[j] * we[lane + j * 64];
#pragma unroll
    for (int off = 32; off > 0; off >>= 1) s += __shfl_down(s, off);
    if (lane == 0) lg[e] = s;
  }
  {
    float s = 0.f;
#pragma unroll
    for (int j = 0; j < 32; ++j) s += xv[j] * wshg[lane + j * 64];
#pragma unroll
    for (int off = 32; off > 0; off >>= 1) s += __shfl_down(s, off);
    if (lane == 0) shg[t] = 1.f / (1.f + expf(-s));
  }
  if (lane == 0) {
    unsigned used = 0;
    int sel[KTOP];
    float val[KTOP];
    for (int k = 0; k < KTOP; ++k) {
      float bv = -1e30f; int bi = 0;
      for (int e = 0; e < EE; ++e)
        if (!((used >> e) & 1) && lg[e] > bv) { bv = lg[e]; bi = e; }
      used |= (1u << bi);
      sel[k] = bi; val[k] = bv;
    }
    float mx = val[0], sum = 0.f;
    for (int k = 0; k < KTOP; ++k) { val[k] = expf(val[k] - mx); sum += val[k]; }
    float inv = 1.f / sum;
    for (int k = 0; k < KTOP; ++k) {
      int e = sel[k];
      int pos = atomicAdd(&cnt[e], 1);
      pair_pos[t * KTOP + k] = pos;
      if (pos < CAP) {
        slot_tok[e * CAP + pos] = t;
        slot_w[e * CAP + pos] = val[k] * inv;
        slot_pair[e * CAP + pos] = t * KTOP + k;
      }
    }
  }
}

// ---------------- grouped GEMM: C = A (rows x K, f16) * B (N x K, f32)^T ----
// r3-verbatim pipeline: sA[3] via global_load_lds (pre-swizzled source),
// sB[2] reg-staged with fused dequant; 1 s_barrier per K-tile; vmcnt(12).
// EPI: 0 = f16 OutH tile; 1 = f16 scatter w*val -> OutH[pair*DD] (pairMap in
// slot_tok arg); 2 = OutF[row] += shg[row]*val.
template<bool DUAL, bool GATHER, bool DEQ, int EPI, int NPB, int MBB, int KDIM>
__global__ __launch_bounds__(256, 2) void k_gemm(
    const _Float16* __restrict__ A,
    const float* __restrict__ B0f, const float* __restrict__ B1f,
    const float* __restrict__ S0, const float* __restrict__ S1,
    int sCols, int sStrideE,
    _Float16* __restrict__ OutH, float* __restrict__ OutF,
    const float* __restrict__ shg,
    int ldA, int ldOut,
    long long strideAE, long long strideBE, long long strideOE,
    const int* __restrict__ cnt, int rowsConst,
    const int* __restrict__ slot_tok, const float* __restrict__ slot_w) {
  constexpr int BK = 64;
  constexpr int KT = KDIM / BK;              // 32 / 12 (all even)
  constexpr int NF = DUAL ? 2 : 4;
  constexpr int BN = DUAL ? 64 : 128;
  constexpr int BCH = DUAL ? 4 : 8;          // float4 staging chunks / thread / op

  // bijective XCD swizzle: all m-blocks of pair (n,e) adjacent on one XCD
  const int f = blockIdx.x;
  const int xcd = f & 7;
  const int t0 = f >> 3;
  const int mb = t0 % MBB;
  const int pp = t0 / MBB;
  const int p  = pp * 8 + xcd;               // (NPB*E) % 8 == 0 for all uses
  const int nb = p % NPB;
  const int e  = p / NPB;

  int rows = cnt ? (cnt[e] > CAP ? CAP : cnt[e]) : rowsConst;
  const int rowBase = mb * 128;
  if (rowBase >= rows) return;
  const int nBase = nb * BN;

  const int tid = threadIdx.x;
  const int lane = tid & 63;
  const int wave = tid >> 6;
  const int wr = wave >> 1;
  const int wc = wave & 1;

  __shared__ __align__(16) _Float16 sA[3][8192];   // 48 KB
  __shared__ __align__(16) _Float16 sB[2][8192];   // 32 KB  (total 81920 B)

  const _Float16* Ae = A + (GATHER ? 0 : (long long)e * strideAE);
  const float* B0e = B0f + (long long)e * strideBE;
  const float* B1e = DUAL ? (B1f + (long long)e * strideBE) : nullptr;
  const float* S0e = DEQ ? (S0 + (long long)e * sStrideE) : nullptr;
  const float* S1e = (DEQ && DUAL) ? (S1 + (long long)e * sStrideE) : nullptr;
  const int sRow = DEQ ? (nBase >> 7) * sCols : 0;

  // A staging (global_load_lds): LDS dest linear, source col pre-swizzled
  int aByte[4];
#pragma unroll
  for (int i = 0; i < 4; ++i) {
    int c = tid + i * 256;                   // 16B chunk id [0,1024)
    int row = c >> 3;                        // tile row 0..127
    int colB = ((c & 7) << 4) ^ ((row & 7) << 4);
    int src = GATHER ? slot_tok[e * CAP + rowBase + row] : (rowBase + row);
    aByte[i] = src * (2 * ldA) + colB;
  }
  // B staging: reg->cvt->swizzled LDS write
  int bOff[BCH], wByte[BCH];
#pragma unroll
  for (int i = 0; i < BCH; ++i) {
    int c = tid + i * 256;
    int rn = c >> 4;                         // [0, BN)
    int c4 = (c & 15) << 2;                  // f32 col 0..60 step 4
    bOff[i] = (nBase + rn) * KDIM + c4;
    wByte[i] = ((rn << 7) + (c4 << 1)) ^ ((rn & 7) << 4);
  }

  f32x4 accG[4][NF];
  f32x4 accU[DUAL ? 4 : 1][NF];
#pragma unroll
  for (int m = 0; m < 4; ++m)
#pragma unroll
    for (int n = 0; n < NF; ++n) {
      accG[m][n] = (f32x4){0.f, 0.f, 0.f, 0.f};
      if constexpr (DUAL) accU[m][n] = (f32x4){0.f, 0.f, 0.f, 0.f};
    }

  auto stageA = [&](int kt, int buf) {       // 4 DMA ops
#pragma unroll
    for (int i = 0; i < 4; ++i) {
      __builtin_amdgcn_global_load_lds(
          (const __attribute__((address_space(1))) void*)
              ((const char*)Ae + aByte[i] + kt * (BK * 2)),
          (__attribute__((address_space(3))) void*)&sA[buf][(tid + i * 256) * 8],
          16, 0, 0);
    }
  };
  auto loadB = [&](int kt, float4 (&r0)[BCH], float4 (&r1)[BCH]) {  // 8 loads
    const int ko = kt * BK;
#pragma unroll
    for (int i = 0; i < BCH; ++i) r0[i] = *(const float4*)(B0e + bOff[i] + ko);
    if constexpr (DUAL) {
#pragma unroll
      for (int i = 0; i < BCH; ++i) r1[i] = *(const float4*)(B1e + bOff[i] + ko);
    }
  };
  auto storeB = [&](int kt, float4 (&r0)[BCH], float4 (&r1)[BCH]) {
    float s0 = 1.f, s1 = 1.f;
    if constexpr (DEQ) {
      s0 = S0e[sRow + (kt >> 1)];
      if constexpr (DUAL) s1 = S1e[sRow + (kt >> 1)];
    }
    char* base = (char*)&sB[kt & 1][0];
#pragma unroll
    for (int i = 0; i < BCH; ++i) {
      half4v h = { (_Float16)(r0[i].x * s0), (_Float16)(r0[i].y * s0),
                   (_Float16)(r0[i].z * s0), (_Float16)(r0[i].w * s0) };
      *(half4v*)(base + wByte[i]) = h;
      if constexpr (DUAL) {
        half4v h1 = { (_Float16)(r1[i].x * s1), (_Float16)(r1[i].y * s1),
                      (_Float16)(r1[i].z * s1), (_Float16)(r1[i].w * s1) };
        *(half4v*)(base + 8192 + wByte[i]) = h1;
      }
    }
  };
  auto computeTile = [&](int ia, int ib) {
    const char* pA = (const char*)&sA[ia][0];
    const char* pB = (const char*)&sB[ib][0];
#pragma unroll
    for (int kk = 0; kk < 2; ++kk) {
      const int koff = kk * 32 + (lane >> 4) * 8;    // f16 elems
      half8 a[4];
#pragma unroll
      for (int m = 0; m < 4; ++m) {
        int r = wr * 64 + m * 16 + (lane & 15);
        int byt = ((r << 7) + (koff << 1)) ^ ((r & 7) << 4);
        a[m] = *(const half8*)(pA + byt);
      }
      if constexpr (DUAL) {
        half8 bg[2], bu[2];
#pragma unroll
        for (int n = 0; n < 2; ++n) {
          int rn = wc * 32 + n * 16 + (lane & 15);
          int byt = ((rn << 7) + (koff << 1)) ^ ((rn & 7) << 4);
          bg[n] = *(const half8*)(pB + byt);
          bu[n] = *(const half8*)(pB + 8192 + byt);
        }
#pragma unroll
        for (int m = 0; m < 4; ++m)
#pragma unroll
          for (int n = 0; n < 2; ++n) {
            accG[m][n] = __builtin_amdgcn_mfma_f32_16x16x32_f16(a[m], bg[n], accG[m][n], 0, 0, 0);
            accU[m][n] = __builtin_amdgcn_mfma_f32_16x16x32_f16(a[m], bu[n], accU[m][n], 0, 0, 0);
          }
      } else {
        half8 b[4];
#pragma unroll
        for (int n = 0; n < 4; ++n) {
          int rn = wc * 64 + n * 16 + (lane & 15);
          int byt = ((rn << 7) + (koff << 1)) ^ ((rn & 7) << 4);
          b[n] = *(const half8*)(pB + byt);
        }
#pragma unroll
        for (int m = 0; m < 4; ++m)
#pragma unroll
          for (int n = 0; n < 4; ++n)
            accG[m][n] = __builtin_amdgcn_mfma_f32_16x16x32_f16(a[m], b[n], accG[m][n], 0, 0, 0);
      }
    }
  };

  // even/odd named register sets (no runtime-indexed reg arrays -> no scratch)
  float4 rbE0[BCH], rbE1[BCH], rbO0[BCH], rbO1[BCH];

  // prologue: tiles 0 and 1 in flight (12 ops each; keep issue groups ordered)
  stageA(0, 0); loadB(0, rbE0, rbE1);
  __builtin_amdgcn_sched_barrier(0);
  stageA(1, 1); loadB(1, rbO0, rbO1);
  __builtin_amdgcn_sched_barrier(0);

  int bufC = 0;   // sA buffer of current tile
  int bufW = 2;   // sA buffer for next issued tile

  for (int kt = 0; kt < KT; kt += 2) {
    // ---------- even tile kt ----------
    if (kt + 1 < KT) { asm volatile("s_waitcnt vmcnt(12)" ::: "memory"); }
    else             { asm volatile("s_waitcnt vmcnt(0)"  ::: "memory"); }
    __builtin_amdgcn_sched_barrier(0);
    storeB(kt, rbE0, rbE1);
    asm volatile("s_waitcnt lgkmcnt(0)" ::: "memory");
    __builtin_amdgcn_sched_barrier(0);
    __builtin_amdgcn_s_barrier();
    __builtin_amdgcn_sched_barrier(0);
    if (kt + 2 < KT) { stageA(kt + 2, bufW); loadB(kt + 2, rbE0, rbE1); }
    __builtin_amdgcn_sched_barrier(0);
    computeTile(bufC, 0);
    bufC = (bufC == 2) ? 0 : bufC + 1;
    bufW = (bufW == 2) ? 0 : bufW + 1;

    // ---------- odd tile kt+1 ----------
    if (kt + 2 < KT) { asm volatile("s_waitcnt vmcnt(12)" ::: "memory"); }
    else             { asm volatile("s_waitcnt vmcnt(0)"  ::: "memory"); }
    __builtin_amdgcn_sched_barrier(0);
    storeB(kt + 1, rbO0, rbO1);
    asm volatile("s_waitcnt lgkmcnt(0)" ::: "memory");
    __builtin_amdgcn_sched_barrier(0);
    __builtin_amdgcn_s_barrier();
    __builtin_amdgcn_sched_barrier(0);
    if (kt + 3 < KT) { stageA(kt + 3, bufW); loadB(kt + 3, rbO0, rbO1); }
    __builtin_amdgcn_sched_barrier(0);
    computeTile(bufC, 1);
    bufC = (bufC == 2) ? 0 : bufC + 1;
    bufW = (bufW == 2) ? 0 : bufW + 1;
  }

  // epilogue; C/D layout: col = lane&15, row = (lane>>4)*4 + i (verified)
#pragma unroll
  for (int m = 0; m < 4; ++m) {
#pragma unroll
    for (int i = 0; i < 4; ++i) {
      int row = rowBase + wr * 64 + m * 16 + (lane >> 4) * 4 + i;
      if (row < rows) {
        if constexpr (EPI == 1) {
          // atomic-free scatter: Yp[pair] = (f16)(w * val); pair map passed
          // via slot_tok arg (slot -> t*8+k). Combine kernel sums per token.
          int pair = slot_tok[e * CAP + row];
          float w = slot_w[e * CAP + row];
#pragma unroll
          for (int n = 0; n < NF; ++n) {
            int col = nBase + wc * 64 + n * 16 + (lane & 15);
            OutH[(long long)pair * DD + col] = (_Float16)(w * accG[m][n][i]);
          }
        } else if constexpr (EPI == 2) {
          float g = shg[row];
#pragma unroll
          for (int n = 0; n < NF; ++n) {
            int col = nBase + wc * 64 + n * 16 + (lane & 15);
            long long o = (long long)row * DD + col;
            OutF[o] += g * accG[m][n][i];
          }
        } else {
          long long outBase = (long long)e * strideOE;
#pragma unroll
          for (int n = 0; n < NF; ++n) {
            int col = nBase + (DUAL ? wc * 32 : wc * 64) + n * 16 + (lane & 15);
            long long o = outBase + (long long)row * ldOut + col;
            if constexpr (DUAL) {
              float gv = accG[m][n][i];
              float uv = accU[m][n][i];
              OutH[o] = (_Float16)((gv / (1.f + __expf(-gv))) * uv);
            } else {
              OutH[o] = (_Float16)accG[m][n][i];
            }
          }
        }
      }
    }
  }
}

// ---------------- combine: out[t] = sum_k (pos<CAP) Yp[t*8+k]  --------------
// (w already folded into Yp by the down-GEMM epilogue; shared-down += after)
__global__ __launch_bounds__(256) void k_combine(
    const _Float16* __restrict__ Yp, const int* __restrict__ pair_pos,
    float* __restrict__ out) {
  int t = blockIdx.x;
  int col = threadIdx.x * 8;
  float acc[8] = {0.f, 0.f, 0.f, 0.f, 0.f, 0.f, 0.f, 0.f};
#pragma unroll
  for (int k = 0; k < KTOP; ++k) {
    if (pair_pos[t * KTOP + k] < CAP) {
      half8 y = *(const half8*)&Yp[((size_t)t * KTOP + k) * DD + col];
#pragma unroll
      for (int j = 0; j < 8; ++j) acc[j] += (float)y[j];
    }
  }
  float4 o0 = {acc[0], acc[1], acc[2], acc[3]};
  float4 o1 = {acc[4], acc[5], acc[6], acc[7]};
  *(float4*)&out[(size_t)t * DD + col] = o0;
  *(float4*)&out[(size_t)t * DD + col + 4] = o1;
}

// ---------------------------------------------------------------------------
extern "C" void kernel_launch(void* const* d_in, const int* in_sizes, int n_in,
                              void* d_out, int out_size, void* d_ws, size_t ws_size,
                              hipStream_t stream) {
  (void)in_sizes; (void)n_in; (void)out_size; (void)ws_size;
  const float* x    = (const float*)d_in[0];
  const float* rw   = (const float*)d_in[1];
  const float* wg   = (const float*)d_in[2];
  const float* sg   = (const float*)d_in[3];
  const float* wu   = (const float*)d_in[4];
  const float* su   = (const float*)d_in[5];
  const float* wd   = (const float*)d_in[6];
  const float* sd   = (const float*)d_in[7];
  const float* wsg  = (const float*)d_in[8];
  const float* wsu  = (const float*)d_in[9];
  const float* wsd  = (const float*)d_in[10];
  const float* wshg = (const float*)d_in[11];
  float* out = (float*)d_out;

  // workspace (~134.5 MB)
  char* p = (char*)d_ws;
  auto alloc = [&](size_t bytes) {
    char* r = p;
    p += (bytes + 255) & ~(size_t)255;
    return r;
  };
  _Float16* x_h   = (_Float16*)alloc((size_t)TT * DD * 2);          //  8.4 MB
  _Float16* H     = (_Float16*)alloc((size_t)EE * CAP * DFF * 2);   // 50.3 MB
  _Float16* Hsh   = (_Float16*)alloc((size_t)TT * DSH * 2);         //  8.4 MB
  _Float16* Yp    = (_Float16*)alloc((size_t)TT * KTOP * DD * 2);   // 67.1 MB
  float* shg      = (float*)alloc((size_t)TT * 4);
  int* cnt        = (int*)alloc((size_t)EE * 4);
  int* slot_tok   = (int*)alloc((size_t)EE * CAP * 4);
  float* slot_w   = (float*)alloc((size_t)EE * CAP * 4);
  int* slot_pair  = (int*)alloc((size_t)EE * CAP * 4);
  int* pair_pos   = (int*)alloc((size_t)TT * KTOP * 4);

  k_init<<<(EE * CAP + 255) / 256, 256, 0, stream>>>(cnt, slot_tok);
  k_cast<<<(TT * DD / 4) / 256, 256, 0, stream>>>(x, x_h);
  k_router<<<TT, 64, 0, stream>>>(x, rw, wshg, shg, cnt, slot_tok, slot_w,
                                  slot_pair, pair_pos);

  // routed gate+up: NP=12, MB=8, E=32 -> 3072 flat blocks
  k_gemm<true, true, true, 0, 12, 8, DD><<<3072, 256, 0, stream>>>(
      x_h, wg, wu, sg, su, DD / 128, (DFF / 128) * (DD / 128),
      H, nullptr, nullptr,
      DD, DFF,
      0LL, (long long)DFF * DD, (long long)CAP * DFF,
      cnt, 0, slot_tok, nullptr);

  // routed down -> Yp (atomic-free; pair map in slot_tok arg): 4096 blocks
  k_gemm<false, false, true, 1, 16, 8, DFF><<<4096, 256, 0, stream>>>(
      H, wd, wd, sd, sd, DFF / 128, (DD / 128) * (DFF / 128),
      Yp, nullptr, nullptr,
      DFF, DD,
      (long long)CAP * DFF, (long long)DD * DFF, 0LL,
      cnt, 0, slot_pair, slot_w);

  // combine: out = sum of each token's 8 weighted pair rows
  k_combine<<<TT, 256, 0, stream>>>(Yp, pair_pos, out);

  // shared gate+up: NP=32, MB=16, E=1 -> 512 blocks
  k_gemm<true, false, false, 0, 32, 16, DD><<<512, 256, 0, stream>>>(
      x_h, wsg, wsu, nullptr, nullptr, 0, 0,
      Hsh, nullptr, nullptr,
      DD, DSH,
      0LL, 0LL, 0LL,
      nullptr, TT, nullptr, nullptr);

  // shared down (out += shg*val, runs last): NP=16, MB=16, E=1 -> 256 blocks
  k_gemm<false, false, false, 2, 16, 16, DSH><<<256, 256, 0, stream>>>(
      Hsh, wsd, wsd, nullptr, nullptr, 0, 0,
      nullptr, out, shg,
      DSH, DD,
      0LL, 0LL, 0LL,
      nullptr, TT, nullptr, nullptr);
}